// Round 19
// baseline (757.105 us; speedup 1.0000x reference)
//
#include <hip/hip_runtime.h>

#define BB 16
#define HH 128
#define WW 128
#define CH 64              // state channels, bf16, one 128B line per pixel
#define TPX 64             // tile width in pixels
#define NTH 512
#define NPIX (BB*HH*WW)
#define KFT 576            // folded GEMM1 K: 9 taps x 64 ch
#define HID 256

// workspace offsets (bytes)
#define WS_WTP 0u              // 294,912 : folded GEMM1 B-fragments bf16 [256][576]
#define WS_WFP 294912u         // 32,768  : GEMM2 B-fragments bf16
#define WS_ST  327680u         // 33,554,432 : bf16 state [NPIX][64]

typedef __attribute__((ext_vector_type(8))) short short8;
typedef __attribute__((ext_vector_type(8))) unsigned short ushort8;
typedef __attribute__((ext_vector_type(4))) float f4;

// LDS layout (bytes) — single 32KB region, serially reused (4 blocks/CU):
//   [0, 32768):  xs [3][66][64]u16 dense 128B rows, chunk-XOR swizzled = 25,344
//                h  [64][256]u16 = 32,768  (overlays xs after B3)
//                stage bf16 [64][64] 8,192 / fp32 [64][64] 16,384 (overlays h after B5)
//   lgs [32768, 33280): life[64] + gate[64] floats
#define OFF_LG  32768
#define SMEM_SZ 33280

// async global->LDS 16B/lane: linear LDS dest (wave base + lane*16), per-lane global src
#define GLDS16(gp, lp) __builtin_amdgcn_global_load_lds( \
    (const __attribute__((address_space(1))) unsigned int*)(gp), \
    (__attribute__((address_space(3))) unsigned int*)(lp), 16, 0, 0)

__device__ __forceinline__ unsigned short f2b(float f) {   // fp32 -> bf16 RTNE
    unsigned x = __float_as_uint(f);
    x += 0x7fffu + ((x >> 16) & 1u);
    return (unsigned short)(x >> 16);
}
__device__ __forceinline__ float b2f(unsigned short u) {
    return __uint_as_float(((unsigned)u) << 16);
}
__device__ __forceinline__ int refl(int i, int n) {
    if (i < 0) return -i;
    if (i >= n) return 2*n - 2 - i;
    return i;
}
// xs addressing: row (0..197), chunk (0..7); short-index of 16B chunk base.
// Row stride 64 shorts = 128B; chunk XOR (row&7) spreads banks (T2).
__device__ __forceinline__ int xrow(int row, int chunk) {
    return row*64 + (((chunk ^ row) & 7) << 3);
}

// prep: folded W~ = conv-folded Wh into MFMA B-fragment order (bf16).
// W~_t[o][c] = Wh[o][64+c]*w1[c][t] + Wh[o][128+c]*w2[c][t] + (t==4)*Wh[o][c]
// (tap t: w-offset i2 = t/3, h-offset j = t%3; verified r2 + r18)
// wtp: o-tile ti (0..15) x ks (0..17): frag g = (ti*18+ks)*64 + l
// wfp: c-tile cq (0..3) x ks2 (0..7): frag g = (cq*8+ks2)*64 + l
__global__ __launch_bounds__(256) void prep(
    const float* __restrict__ wh, const float* __restrict__ wf,
    const float* __restrict__ w1, const float* __restrict__ w2,
    unsigned short* __restrict__ wtp, unsigned short* __restrict__ wfp)
{
    int i = blockIdx.x * 256 + threadIdx.x;   // 20480 groups
    if (i < 18432) {
        const int l = i & 63, r = i >> 6;
        const int ks = r % 18, ti = r / 18;
        const int o  = ti*16 + (l & 15);
        const int k0 = ks*32 + (l >> 4)*8;
        ushort8 v;
        #pragma unroll
        for (int j = 0; j < 8; ++j) {
            const int k = k0 + j;
            const int t = k >> 6, c = k & 63;
            float val = wh[o*192 + 64 + c]  * w1[c*9 + t]
                      + wh[o*192 + 128 + c] * w2[c*9 + t];
            if (t == 4) val += wh[o*192 + c];
            v[j] = f2b(val);
        }
        *(ushort8*)&wtp[(size_t)i * 8] = v;
    } else if (i < 20480) {
        const int g = i - 18432;              // 2048 groups
        const int l = g & 63, r = g >> 6;
        const int ks2 = r & 7, cq = r >> 3;
        const int c  = cq*16 + (l & 15);
        const int o0 = ks2*32 + (l >> 4)*8;
        ushort8 v;
        #pragma unroll
        for (int j = 0; j < 8; ++j) v[j] = f2b(wf[c*HID + o0 + j]);
        *(ushort8*)&wfp[(size_t)g * 8] = v;
    }
}

// SRCF: 0 = src is xin (64ch fp32 raw), 1 = src is bf16 state64 (line-aligned)
// DSTF: 0 = dst is bf16 state64, 1 = dst is out (64ch fp32)
template<int SRCF, int DSTF>
__global__ __launch_bounds__(512, 8) void nca_step(
    const float* __restrict__ xinf, const unsigned short* __restrict__ srcb,
    void* __restrict__ dstv,
    const unsigned short* __restrict__ wtp, const unsigned short* __restrict__ wfp,
    const float* __restrict__ bh, const float* __restrict__ rnd)
{
    __shared__ __align__(16) char smem[SMEM_SZ];
    unsigned short* xs  = (unsigned short*)smem;
    float*          lgs = (float*)(smem + OFF_LG);

    const int tid = threadIdx.x;
    const int l = tid & 63, wv = tid >> 6;
    const int lr = l & 15, gq = l >> 4;
    const int w0 = blockIdx.x * TPX;
    const int h  = blockIdx.y;
    const int b  = blockIdx.z;
    const int R  = b * HH + h;

    // ---- phase 1: halo staging (async DMA for state path), gate ----
    if (SRCF == 1) {
        // linear LDS dest; inverse chunk-swizzle on SOURCE (rule 21); readers use xrow()
        #pragma unroll
        for (int it = 0; it < 3; ++it) {
            const int g = wv + it*8;              // wave-uniform group, 24 full groups
            const int c = g*64 + l;
            const int row = c >> 3, ckp = c & 7;
            const int r3 = row / 66, px = row - r3*66;
            const int ck = ckp ^ (row & 7);
            const int sr = refl(h - 1 + r3, HH);
            const int sc = refl(w0 - 1 + px, WW);
            const unsigned short* gp = srcb + ((((size_t)b*HH + sr)*WW + sc) << 6) + (ck << 3);
            GLDS16(gp, (char*)xs + (size_t)g*1024);
        }
        if (wv == 0 && l < 48) {                  // remainder: chunks 1536..1583
            const int c = 1536 + l;
            const int row = c >> 3, ckp = c & 7;
            const int r3 = row / 66, px = row - r3*66;
            const int ck = ckp ^ (row & 7);
            const int sr = refl(h - 1 + r3, HH);
            const int sc = refl(w0 - 1 + px, WW);
            const unsigned short* gp = srcb + ((((size_t)b*HH + sr)*WW + sc) << 6) + (ck << 3);
            GLDS16(gp, (char*)xs + (size_t)24*1024);
        }
    } else {
        const int q = tid & 3;
        for (int s0 = tid >> 2; s0 < 198; s0 += 128) {
            const int r3 = s0 / 66, wi = s0 - r3*66;
            const int sr = refl(h - 1 + r3, HH);
            const int sc = refl(w0 - 1 + wi, WW);
            const size_t pix = ((size_t)b*HH + sr)*WW + sc;
            const float* p = xinf + pix*64 + q*16;
            f4 a0 = *(const f4*)p, a1 = *(const f4*)(p+4);
            f4 a2 = *(const f4*)(p+8), a3 = *(const f4*)(p+12);
            ushort8 o0, o1;
            o0[0]=f2b(a0.x); o0[1]=f2b(a0.y); o0[2]=f2b(a0.z); o0[3]=f2b(a0.w);
            o0[4]=f2b(a1.x); o0[5]=f2b(a1.y); o0[6]=f2b(a1.z); o0[7]=f2b(a1.w);
            o1[0]=f2b(a2.x); o1[1]=f2b(a2.y); o1[2]=f2b(a2.z); o1[3]=f2b(a2.w);
            o1[4]=f2b(a3.x); o1[5]=f2b(a3.y); o1[6]=f2b(a3.z); o1[7]=f2b(a3.w);
            const int row = r3*66 + wi;
            *(ushort8*)(xs + xrow(row, 2*q))     = o0;
            *(ushort8*)(xs + xrow(row, 2*q + 1)) = o1;
        }
    }
    if (tid < TPX) {
        const size_t pix = (size_t)R * WW + w0 + tid;
        lgs[TPX + tid] = (rnd[pix] > 0.5f) ? 1.f : 0.f;
        if (SRCF == 0)
            lgs[tid] = (xinf[pix*64] > 0.f) ? 1.f : 0.f;
    }
    __syncthreads();                                          // B1 (drains vmcnt)

    if (SRCF == 1 && tid < TPX)
        lgs[tid] = (b2f(xs[xrow(66 + tid + 1, 0)]) > 0.f) ? 1.f : 0.f;

    // ---- phase 2: folded GEMM1 h = relu(W~ . x_halo + b), K = 576
    //      wave wv owns o-slice [wv*32, wv*32+32), Mt=4 x Ot=2 ----
    f4 acc[4][2];
    #pragma unroll
    for (int ot = 0; ot < 2; ++ot) {
        const float bv = bh[wv*32 + ot*16 + lr];
        const f4 bvv = {bv, bv, bv, bv};
        #pragma unroll
        for (int mt = 0; mt < 4; ++mt) acc[mt][ot] = bvv;
    }
    #pragma unroll
    for (int ks = 0; ks < 18; ++ks) {
        const int t = ks >> 1, half = ks & 1;    // tap t: i2 = t/3 (w-off), j = t%3 (h-off)
        const int i2 = t / 3, j = t - 3*i2;
        short8 afr[4];
        #pragma unroll
        for (int mt = 0; mt < 4; ++mt) {
            const int px = mt*16 + lr;
            afr[mt] = *(const short8*)(xs + xrow(j*66 + px + i2, half*4 + gq));
        }
        #pragma unroll
        for (int ot = 0; ot < 2; ++ot) {
            const short8 bfr = *(const short8*)(wtp + ((((wv*2 + ot)*18 + ks)*64 + l) << 3));
            #pragma unroll
            for (int mt = 0; mt < 4; ++mt)
                acc[mt][ot] = __builtin_amdgcn_mfma_f32_16x16x32_bf16(afr[mt], bfr, acc[mt][ot], 0,0,0);
        }
    }

    // epilogue base values from xs (still intact; all 64 channels valid)
    const int cq = wv & 3, mh = wv >> 2;     // GEMM2 mapping: c-tile, px-half
    unsigned short baseb[8];
    #pragma unroll
    for (int mt = 0; mt < 2; ++mt)
      #pragma unroll
      for (int r2 = 0; r2 < 4; ++r2) {
        const int px = mh*32 + mt*16 + gq*4 + r2;
        baseb[mt*4 + r2] = xs[xrow(66 + px + 1, cq*2 + (lr >> 3)) + (lr & 7)];
      }
    __syncthreads();                                          // B3 (xs reads done)

    // h (bf16, swizzled 512B rows) overlays xs
    #pragma unroll
    for (int mt = 0; mt < 4; ++mt)
      #pragma unroll
      for (int ot = 0; ot < 2; ++ot)
        #pragma unroll
        for (int r2 = 0; r2 < 4; ++r2) {
            const int px = mt*16 + gq*4 + r2;
            const int o  = wv*32 + ot*16 + lr;
            *(unsigned short*)(smem + ((px*512 + o*2) ^ ((px & 7) << 4))) =
                f2b(fmaxf(acc[mt][ot][r2], 0.f));
        }
    __syncthreads();                                          // B4

    // ---- phase 3: GEMM2; wave = (px-half mh, c-tile cq), Mt=2 x Ct=1 ----
    f4 acc2[2] = {{0.f,0.f,0.f,0.f},{0.f,0.f,0.f,0.f}};
    #pragma unroll
    for (int ks2 = 0; ks2 < 8; ++ks2) {
        const short8 bw = *(const short8*)(wfp + (((cq*8 + ks2)*64 + l) << 3));
        #pragma unroll
        for (int mt = 0; mt < 2; ++mt) {
            const int px = mh*32 + mt*16 + lr;
            const short8 ha = *(const short8*)(smem + ((px*512 + ks2*64 + gq*16) ^ ((px & 7) << 4)));
            acc2[mt] = __builtin_amdgcn_mfma_f32_16x16x32_bf16(ha, bw, acc2[mt], 0,0,0);
        }
    }
    __syncthreads();                                          // B5 (h reads done)

    // ---- epilogue: gate + mask + life -> stage (overlays h region) ----
    unsigned short* stageB = (unsigned short*)smem;   // DSTF==0: [64][64] bf16
    float*          stageF = (float*)smem;            // DSTF==1: [64][64] fp32
    #pragma unroll
    for (int mt = 0; mt < 2; ++mt)
      #pragma unroll
      for (int r2 = 0; r2 < 4; ++r2) {
        const int px = mh*32 + mt*16 + gq*4 + r2;
        const int c  = cq*16 + lr;
        const float life = lgs[px], g = lgs[TPX + px];
        const float base = b2f(baseb[mt*4 + r2]);
        const float dx   = acc2[mt][r2];
        const float outv = (c >= 4) ? (base + dx * g) * life : base * life;
        if (DSTF == 1) stageF[px*64 + c] = outv;
        else           stageB[px*64 + c] = f2b(outv);
      }
    __syncthreads();                                          // B6

    // ---- coalesced full-line store (non-temporal; dst has no reuse) ----
    const size_t pix0 = (size_t)R * WW + w0;
    if (DSTF == 1) {
        float* dstf = (float*)dstv + pix0 * 64;
        for (int i = tid; i < 1024; i += NTH) {
            const f4 v = *(const f4*)(stageF + i*4);
            __builtin_nontemporal_store(v, (f4*)(dstf + i*4));
        }
    } else {
        unsigned short* dstb = (unsigned short*)dstv + pix0 * 64;
        const ushort8 v = *(const ushort8*)(stageB + tid*8);
        __builtin_nontemporal_store(v, (ushort8*)(dstb + tid*8));
    }
}

extern "C" void kernel_launch(void* const* d_in, const int* in_sizes, int n_in,
                              void* d_out, int out_size, void* d_ws, size_t ws_size,
                              hipStream_t stream) {
    const float* xin = (const float*)d_in[0];
    const float* w1  = (const float*)d_in[1];
    const float* w2  = (const float*)d_in[2];
    const float* wh  = (const float*)d_in[3];
    const float* bh  = (const float*)d_in[4];
    const float* wf  = (const float*)d_in[5];
    const float* rv  = (const float*)d_in[6];

    unsigned short* wtp = (unsigned short*)((char*)d_ws + WS_WTP);
    unsigned short* wfp = (unsigned short*)((char*)d_ws + WS_WFP);
    unsigned short* stb = (unsigned short*)((char*)d_ws + WS_ST);   // bf16 state A
    unsigned short* omb = (unsigned short*)d_out;                   // bf16 state B (scratch)

    prep<<<dim3(80), dim3(256), 0, stream>>>(wh, wf, w1, w2, wtp, wfp);

    dim3 g(WW / TPX, HH, BB), blk(NTH);
    nca_step<0,0><<<g, blk, 0, stream>>>(xin, nullptr, stb, wtp, wfp, bh, rv);
    for (int s = 1; s < 7; ++s) {
        const unsigned short* sp = (s & 1) ? stb : omb;
        unsigned short* dp       = (s & 1) ? omb : stb;
        nca_step<1,0><<<g, blk, 0, stream>>>(nullptr, sp, dp, wtp, wfp, bh,
                                             rv + (size_t)s * NPIX);
    }
    nca_step<1,1><<<g, blk, 0, stream>>>(nullptr, stb, d_out, wtp, wfp, bh,
                                         rv + (size_t)7 * NPIX);
}

// Round 20
// 724.658 us; speedup vs baseline: 1.0448x; 1.0448x over previous
//
#include <hip/hip_runtime.h>

#define BB 16
#define HH 128
#define WW 128
#define CH 64              // state channels, bf16, one 128B line per pixel
#define TPX 64             // tile width in pixels
#define NTH 512
#define NPIX (BB*HH*WW)
#define KFT 576            // folded GEMM1 K: 9 taps x 64 ch
#define HID 256

// workspace offsets (bytes)
#define WS_WTP 0u              // 294,912 : folded GEMM1 B-fragments bf16 [256][576]
#define WS_WFP 294912u         // 32,768  : GEMM2 B-fragments bf16
#define WS_ST  327680u         // 33,554,432 : bf16 state [NPIX][64]

typedef __attribute__((ext_vector_type(8))) short short8;
typedef __attribute__((ext_vector_type(8))) unsigned short ushort8;
typedef __attribute__((ext_vector_type(4))) float f4;

// LDS layout (bytes) — single 32KB region, serially reused (4 blocks/CU):
//   [0, 32768):  xs [3][66][64]u16 dense 128B rows, chunk-XOR swizzled = 25,344
//                h  [64][256]u16 = 32,768  (overlays xs after B3)
//                stage bf16 [64][64] 8,192 / fp32 [64][64] 16,384 (overlays h after B5)
//   lgs [32768, 33280): life[64] + gate[64] floats
#define OFF_LG  32768
#define SMEM_SZ 33280

// async global->LDS 16B/lane: linear LDS dest (wave base + lane*16), per-lane global src
#define GLDS16(gp, lp) __builtin_amdgcn_global_load_lds( \
    (const __attribute__((address_space(1))) unsigned int*)(gp), \
    (__attribute__((address_space(3))) unsigned int*)(lp), 16, 0, 0)

__device__ __forceinline__ unsigned short f2b(float f) {   // fp32 -> bf16 RTNE
    unsigned x = __float_as_uint(f);
    x += 0x7fffu + ((x >> 16) & 1u);
    return (unsigned short)(x >> 16);
}
__device__ __forceinline__ float b2f(unsigned short u) {
    return __uint_as_float(((unsigned)u) << 16);
}
__device__ __forceinline__ int refl(int i, int n) {
    if (i < 0) return -i;
    if (i >= n) return 2*n - 2 - i;
    return i;
}
// xs addressing: row (0..197), chunk (0..7); short-index of 16B chunk base.
// Row stride 64 shorts = 128B; chunk XOR (row&7) spreads banks (T2).
__device__ __forceinline__ int xrow(int row, int chunk) {
    return row*64 + (((chunk ^ row) & 7) << 3);
}

// prep: folded W~ = conv-folded Wh into MFMA B-fragment order (bf16).
// W~_t[o][c] = Wh[o][64+c]*w1[c][t] + Wh[o][128+c]*w2[c][t] + (t==4)*Wh[o][c]
// (tap t: w-offset i2 = t/3, h-offset j = t%3; verified r2 + r18)
// wtp: o-tile ti (0..15) x ks (0..17): frag g = (ti*18+ks)*64 + l
// wfp: c-tile cq (0..3) x ks2 (0..7): frag g = (cq*8+ks2)*64 + l
__global__ __launch_bounds__(256) void prep(
    const float* __restrict__ wh, const float* __restrict__ wf,
    const float* __restrict__ w1, const float* __restrict__ w2,
    unsigned short* __restrict__ wtp, unsigned short* __restrict__ wfp)
{
    int i = blockIdx.x * 256 + threadIdx.x;   // 20480 groups
    if (i < 18432) {
        const int l = i & 63, r = i >> 6;
        const int ks = r % 18, ti = r / 18;
        const int o  = ti*16 + (l & 15);
        const int k0 = ks*32 + (l >> 4)*8;
        ushort8 v;
        #pragma unroll
        for (int j = 0; j < 8; ++j) {
            const int k = k0 + j;
            const int t = k >> 6, c = k & 63;
            float val = wh[o*192 + 64 + c]  * w1[c*9 + t]
                      + wh[o*192 + 128 + c] * w2[c*9 + t];
            if (t == 4) val += wh[o*192 + c];
            v[j] = f2b(val);
        }
        *(ushort8*)&wtp[(size_t)i * 8] = v;
    } else if (i < 20480) {
        const int g = i - 18432;              // 2048 groups
        const int l = g & 63, r = g >> 6;
        const int ks2 = r & 7, cq = r >> 3;
        const int c  = cq*16 + (l & 15);
        const int o0 = ks2*32 + (l >> 4)*8;
        ushort8 v;
        #pragma unroll
        for (int j = 0; j < 8; ++j) v[j] = f2b(wf[c*HID + o0 + j]);
        *(ushort8*)&wfp[(size_t)g * 8] = v;
    }
}

// SRCF: 0 = src is xin (64ch fp32 raw), 1 = src is bf16 state64 (line-aligned)
// DSTF: 0 = dst is bf16 state64, 1 = dst is out (64ch fp32)
template<int SRCF, int DSTF>
__global__ __launch_bounds__(512, 4) void nca_step(
    const float* __restrict__ xinf, const unsigned short* __restrict__ srcb,
    void* __restrict__ dstv,
    const unsigned short* __restrict__ wtp, const unsigned short* __restrict__ wfp,
    const float* __restrict__ bh, const float* __restrict__ rnd)
{
    __shared__ __align__(16) char smem[SMEM_SZ];
    unsigned short* xs  = (unsigned short*)smem;
    float*          lgs = (float*)(smem + OFF_LG);

    const int tid = threadIdx.x;
    const int l = tid & 63, wv = tid >> 6;
    const int lr = l & 15, gq = l >> 4;
    const int w0 = blockIdx.x * TPX;
    const int h  = blockIdx.y;
    const int b  = blockIdx.z;
    const int R  = b * HH + h;

    // ---- phase 1: halo staging (async DMA for state path), gate ----
    if (SRCF == 1) {
        // linear LDS dest; inverse chunk-swizzle on SOURCE (rule 21); readers use xrow()
        #pragma unroll
        for (int it = 0; it < 3; ++it) {
            const int g = wv + it*8;              // wave-uniform group, 24 full groups
            const int c = g*64 + l;
            const int row = c >> 3, ckp = c & 7;
            const int r3 = row / 66, px = row - r3*66;
            const int ck = ckp ^ (row & 7);
            const int sr = refl(h - 1 + r3, HH);
            const int sc = refl(w0 - 1 + px, WW);
            const unsigned short* gp = srcb + ((((size_t)b*HH + sr)*WW + sc) << 6) + (ck << 3);
            GLDS16(gp, (char*)xs + (size_t)g*1024);
        }
        if (wv == 0 && l < 48) {                  // remainder: chunks 1536..1583
            const int c = 1536 + l;
            const int row = c >> 3, ckp = c & 7;
            const int r3 = row / 66, px = row - r3*66;
            const int ck = ckp ^ (row & 7);
            const int sr = refl(h - 1 + r3, HH);
            const int sc = refl(w0 - 1 + px, WW);
            const unsigned short* gp = srcb + ((((size_t)b*HH + sr)*WW + sc) << 6) + (ck << 3);
            GLDS16(gp, (char*)xs + (size_t)24*1024);
        }
    } else {
        const int q = tid & 3;
        for (int s0 = tid >> 2; s0 < 198; s0 += 128) {
            const int r3 = s0 / 66, wi = s0 - r3*66;
            const int sr = refl(h - 1 + r3, HH);
            const int sc = refl(w0 - 1 + wi, WW);
            const size_t pix = ((size_t)b*HH + sr)*WW + sc;
            const float* p = xinf + pix*64 + q*16;
            f4 a0 = *(const f4*)p, a1 = *(const f4*)(p+4);
            f4 a2 = *(const f4*)(p+8), a3 = *(const f4*)(p+12);
            ushort8 o0, o1;
            o0[0]=f2b(a0.x); o0[1]=f2b(a0.y); o0[2]=f2b(a0.z); o0[3]=f2b(a0.w);
            o0[4]=f2b(a1.x); o0[5]=f2b(a1.y); o0[6]=f2b(a1.z); o0[7]=f2b(a1.w);
            o1[0]=f2b(a2.x); o1[1]=f2b(a2.y); o1[2]=f2b(a2.z); o1[3]=f2b(a2.w);
            o1[4]=f2b(a3.x); o1[5]=f2b(a3.y); o1[6]=f2b(a3.z); o1[7]=f2b(a3.w);
            const int row = r3*66 + wi;
            *(ushort8*)(xs + xrow(row, 2*q))     = o0;
            *(ushort8*)(xs + xrow(row, 2*q + 1)) = o1;
        }
    }
    if (tid < TPX) {
        const size_t pix = (size_t)R * WW + w0 + tid;
        lgs[TPX + tid] = (rnd[pix] > 0.5f) ? 1.f : 0.f;
        if (SRCF == 0)
            lgs[tid] = (xinf[pix*64] > 0.f) ? 1.f : 0.f;
    }
    __syncthreads();                                          // B1 (drains vmcnt)

    if (SRCF == 1 && tid < TPX)
        lgs[tid] = (b2f(xs[xrow(66 + tid + 1, 0)]) > 0.f) ? 1.f : 0.f;

    // ---- phase 2: folded GEMM1 h = relu(W~ . x_halo + b), K = 576
    //      wave wv owns o-slice [wv*32, wv*32+32), Mt=4 x Ot=2 ----
    f4 acc[4][2];
    #pragma unroll
    for (int ot = 0; ot < 2; ++ot) {
        const float bv = bh[wv*32 + ot*16 + lr];
        const f4 bvv = {bv, bv, bv, bv};
        #pragma unroll
        for (int mt = 0; mt < 4; ++mt) acc[mt][ot] = bvv;
    }
    #pragma unroll
    for (int ks = 0; ks < 18; ++ks) {
        const int t = ks >> 1, half = ks & 1;    // tap t: i2 = t/3 (w-off), j = t%3 (h-off)
        const int i2 = t / 3, j = t - 3*i2;
        short8 afr[4];
        #pragma unroll
        for (int mt = 0; mt < 4; ++mt) {
            const int px = mt*16 + lr;
            afr[mt] = *(const short8*)(xs + xrow(j*66 + px + i2, half*4 + gq));
        }
        #pragma unroll
        for (int ot = 0; ot < 2; ++ot) {
            const short8 bfr = *(const short8*)(wtp + ((((wv*2 + ot)*18 + ks)*64 + l) << 3));
            #pragma unroll
            for (int mt = 0; mt < 4; ++mt)
                acc[mt][ot] = __builtin_amdgcn_mfma_f32_16x16x32_bf16(afr[mt], bfr, acc[mt][ot], 0,0,0);
        }
    }

    // epilogue base values from xs (still intact; all 64 channels valid)
    const int cq = wv & 3, mh = wv >> 2;     // GEMM2 mapping: c-tile, px-half
    unsigned short baseb[8];
    #pragma unroll
    for (int mt = 0; mt < 2; ++mt)
      #pragma unroll
      for (int r2 = 0; r2 < 4; ++r2) {
        const int px = mh*32 + mt*16 + gq*4 + r2;
        baseb[mt*4 + r2] = xs[xrow(66 + px + 1, cq*2 + (lr >> 3)) + (lr & 7)];
      }
    __syncthreads();                                          // B3 (xs reads done)

    // h (bf16, swizzled 512B rows) overlays xs
    #pragma unroll
    for (int mt = 0; mt < 4; ++mt)
      #pragma unroll
      for (int ot = 0; ot < 2; ++ot)
        #pragma unroll
        for (int r2 = 0; r2 < 4; ++r2) {
            const int px = mt*16 + gq*4 + r2;
            const int o  = wv*32 + ot*16 + lr;
            *(unsigned short*)(smem + ((px*512 + o*2) ^ ((px & 7) << 4))) =
                f2b(fmaxf(acc[mt][ot][r2], 0.f));
        }
    __syncthreads();                                          // B4

    // ---- phase 3: GEMM2; wave = (px-half mh, c-tile cq), Mt=2 x Ct=1 ----
    f4 acc2[2] = {{0.f,0.f,0.f,0.f},{0.f,0.f,0.f,0.f}};
    #pragma unroll
    for (int ks2 = 0; ks2 < 8; ++ks2) {
        const short8 bw = *(const short8*)(wfp + (((cq*8 + ks2)*64 + l) << 3));
        #pragma unroll
        for (int mt = 0; mt < 2; ++mt) {
            const int px = mh*32 + mt*16 + lr;
            const short8 ha = *(const short8*)(smem + ((px*512 + ks2*64 + gq*16) ^ ((px & 7) << 4)));
            acc2[mt] = __builtin_amdgcn_mfma_f32_16x16x32_bf16(ha, bw, acc2[mt], 0,0,0);
        }
    }
    __syncthreads();                                          // B5 (h reads done)

    // ---- epilogue: gate + mask + life -> stage (overlays h region) ----
    unsigned short* stageB = (unsigned short*)smem;   // DSTF==0: [64][64] bf16
    float*          stageF = (float*)smem;            // DSTF==1: [64][64] fp32
    #pragma unroll
    for (int mt = 0; mt < 2; ++mt)
      #pragma unroll
      for (int r2 = 0; r2 < 4; ++r2) {
        const int px = mh*32 + mt*16 + gq*4 + r2;
        const int c  = cq*16 + lr;
        const float life = lgs[px], g = lgs[TPX + px];
        const float base = b2f(baseb[mt*4 + r2]);
        const float dx   = acc2[mt][r2];
        const float outv = (c >= 4) ? (base + dx * g) * life : base * life;
        if (DSTF == 1) stageF[px*64 + c] = outv;
        else           stageB[px*64 + c] = f2b(outv);
      }
    __syncthreads();                                          // B6

    // ---- coalesced full-line store (non-temporal; dst has no reuse) ----
    const size_t pix0 = (size_t)R * WW + w0;
    if (DSTF == 1) {
        float* dstf = (float*)dstv + pix0 * 64;
        for (int i = tid; i < 1024; i += NTH) {
            const f4 v = *(const f4*)(stageF + i*4);
            __builtin_nontemporal_store(v, (f4*)(dstf + i*4));
        }
    } else {
        unsigned short* dstb = (unsigned short*)dstv + pix0 * 64;
        const ushort8 v = *(const ushort8*)(stageB + tid*8);
        __builtin_nontemporal_store(v, (ushort8*)(dstb + tid*8));
    }
}

extern "C" void kernel_launch(void* const* d_in, const int* in_sizes, int n_in,
                              void* d_out, int out_size, void* d_ws, size_t ws_size,
                              hipStream_t stream) {
    const float* xin = (const float*)d_in[0];
    const float* w1  = (const float*)d_in[1];
    const float* w2  = (const float*)d_in[2];
    const float* wh  = (const float*)d_in[3];
    const float* bh  = (const float*)d_in[4];
    const float* wf  = (const float*)d_in[5];
    const float* rv  = (const float*)d_in[6];

    unsigned short* wtp = (unsigned short*)((char*)d_ws + WS_WTP);
    unsigned short* wfp = (unsigned short*)((char*)d_ws + WS_WFP);
    unsigned short* stb = (unsigned short*)((char*)d_ws + WS_ST);   // bf16 state A
    unsigned short* omb = (unsigned short*)d_out;                   // bf16 state B (scratch)

    prep<<<dim3(80), dim3(256), 0, stream>>>(wh, wf, w1, w2, wtp, wfp);

    dim3 g(WW / TPX, HH, BB), blk(NTH);
    nca_step<0,0><<<g, blk, 0, stream>>>(xin, nullptr, stb, wtp, wfp, bh, rv);
    for (int s = 1; s < 7; ++s) {
        const unsigned short* sp = (s & 1) ? stb : omb;
        unsigned short* dp       = (s & 1) ? omb : stb;
        nca_step<1,0><<<g, blk, 0, stream>>>(nullptr, sp, dp, wtp, wfp, bh,
                                             rv + (size_t)s * NPIX);
    }
    nca_step<1,1><<<g, blk, 0, stream>>>(nullptr, stb, d_out, wtp, wfp, bh,
                                         rv + (size_t)7 * NPIX);
}

// Round 21
// 610.031 us; speedup vs baseline: 1.2411x; 1.1879x over previous
//
#include <hip/hip_runtime.h>

#define BB 16
#define HH 128
#define WW 128
#define CH 64              // state channels, bf16, one 128B line per pixel
#define TPX 32             // tile width in pixels
#define NTH 256
#define NPIX (BB*HH*WW)
#define KF 192
#define HID 256

// workspace offsets (bytes)
#define WS_WTP 0u              // 98,304  : GEMM1 B-fragments bf16
#define WS_WFP 98304u          // 32,768  : GEMM2 B-fragments bf16
#define WS_WCB 131072u         //  4,608  : conv weights fp32 [2][9][64]
#define WS_ST  135680u         // 33,554,432 : bf16 state [NPIX][64]

typedef __attribute__((ext_vector_type(8))) short short8;
typedef __attribute__((ext_vector_type(8))) unsigned short ushort8;
typedef __attribute__((ext_vector_type(4))) float f4;

// LDS layout (bytes), 26,112 total -> 6 blocks/CU:
//   xs   [3][34][64]u16 dense 128B rows, chunk-XOR swizzled  @ 0      : 13,056
//   Fc   [32][128]u16 (XOR-swizzled rows)                    @ 13,056 :  8,192
//   h    [32][256]u16 swizzled 512B rows, overlays [0,16384) after B3
//   stage bf16/fp32 [32][64]                                 @ 16,384 :  8,192
//         (overlays Fc tail + wcvb, both dead after B3/B2)
//   wcvb fp32 [2][9][64]                                     @ 21,248 :  4,608
//   lgs  life[32]+gate[32] floats                            @ 25,856 :    256
#define OFF_FC  13056
#define OFF_STG 16384
#define OFF_WCV 21248
#define OFF_LG  25856
#define SMEM_SZ 26112

// async global->LDS 16B/lane: linear LDS dest (wave base + lane*16), per-lane global src
#define GLDS16(gp, lp) __builtin_amdgcn_global_load_lds( \
    (const __attribute__((address_space(1))) unsigned int*)(gp), \
    (__attribute__((address_space(3))) unsigned int*)(lp), 16, 0, 0)

__device__ __forceinline__ unsigned short f2b(float f) {   // fp32 -> bf16 RTNE
    unsigned x = __float_as_uint(f);
    x += 0x7fffu + ((x >> 16) & 1u);
    return (unsigned short)(x >> 16);
}
__device__ __forceinline__ float b2f(unsigned short u) {
    return __uint_as_float(((unsigned)u) << 16);
}
__device__ __forceinline__ int refl(int i, int n) {
    if (i < 0) return -i;
    if (i >= n) return 2*n - 2 - i;
    return i;
}
// xs addressing: row (0..101), chunk (0..7); short-index of 16B chunk base.
// Row stride 64 shorts = 128B; chunk XOR (row&7) spreads banks (T2).
__device__ __forceinline__ int xrow(int row, int chunk) {
    return row*64 + (((chunk ^ row) & 7) << 3);
}

// prep: weights into MFMA B-fragment order (bf16). Verified layout (r4-r17).
// wtp: o-tile ti (0..15) x ks (0..5): frag g = (ti*6+ks)*64 + l; o-row = ti*16 + (l&15)
// wfp: c-tile cq (0..3) x ks2 (0..7): frag g = (cq*8+ks2)*64 + l
__global__ __launch_bounds__(256) void prep(
    const float* __restrict__ wh, const float* __restrict__ wf,
    unsigned short* __restrict__ wtp, unsigned short* __restrict__ wfp)
{
    int i = blockIdx.x * 256 + threadIdx.x;   // 8192 groups
    if (i < 6144) {
        const int l = i & 63, r = i >> 6;
        const int ks = r % 6, ti = r / 6;
        const int row = ti*16 + (l & 15);
        const int k0  = ks*32 + (l >> 4)*8;
        ushort8 v;
        #pragma unroll
        for (int j = 0; j < 8; ++j) v[j] = f2b(wh[row*KF + k0 + j]);
        *(ushort8*)&wtp[(size_t)i * 8] = v;
    } else {
        const int g = i - 6144;               // 2048 groups
        const int l = g & 63, r = g >> 6;
        const int ks2 = r & 7, cq = r >> 3;
        const int c  = cq*16 + (l & 15);
        const int o0 = ks2*32 + (l >> 4)*8;
        ushort8 v;
        #pragma unroll
        for (int j = 0; j < 8; ++j) v[j] = f2b(wf[c*HID + o0 + j]);
        *(ushort8*)&wfp[(size_t)g * 8] = v;
    }
}

// prep2: conv weights -> fp32 [filter][tap][ch] (mapping verified r2-r17)
__global__ __launch_bounds__(256) void prep2(
    const float* __restrict__ w1, const float* __restrict__ w2,
    float* __restrict__ wcb)
{
    int i = blockIdx.x * 256 + threadIdx.x;
    if (i < 1152) {
        const int f = i / 576, rem = i - f * 576;
        const int t = rem >> 6, c = rem & 63;
        wcb[i] = (f ? w2 : w1)[c*9 + t];
    }
}

// SRCF: 0 = src is xin (64ch fp32 raw), 1 = src is bf16 state64 (line-aligned)
// DSTF: 0 = dst is bf16 state64, 1 = dst is out (64ch fp32)
template<int SRCF, int DSTF>
__global__ __launch_bounds__(256, 4) void nca_step(
    const float* __restrict__ xinf, const unsigned short* __restrict__ srcb,
    void* __restrict__ dstv,
    const unsigned short* __restrict__ wtp, const unsigned short* __restrict__ wfp,
    const float* __restrict__ wcbg,
    const float* __restrict__ bh, const float* __restrict__ rnd)
{
    __shared__ __align__(16) char smem[SMEM_SZ];
    unsigned short* xs   = (unsigned short*)smem;
    char*           fch  = smem + OFF_FC;
    char*           stg  = smem + OFF_STG;
    float*          wcvb = (float*)(smem + OFF_WCV);
    float*          lgs  = (float*)(smem + OFF_LG);

    const int tid = threadIdx.x;
    const int l = tid & 63, wv = tid >> 6;   // 4 waves
    const int lr = l & 15, gq = l >> 4;
    const int w0 = blockIdx.x * TPX;
    const int h  = blockIdx.y;
    const int b  = blockIdx.z;
    const int R  = b * HH + h;

    // ---- phase 1: halo staging (async DMA for state path), weights, gate ----
    if (SRCF == 1) {
        // linear LDS dest; inverse chunk-swizzle on SOURCE (rule 21); readers use xrow()
        #pragma unroll
        for (int it = 0; it < 3; ++it) {
            const int g = wv + it*4;              // 12 full wave-groups
            const int c = g*64 + l;
            const int row = c >> 3, ckp = c & 7;
            const int r3 = row / 34, px = row - r3*34;
            const int ck = ckp ^ (row & 7);
            const int sr = refl(h - 1 + r3, HH);
            const int sc = refl(w0 - 1 + px, WW);
            const unsigned short* gp = srcb + ((((size_t)b*HH + sr)*WW + sc) << 6) + (ck << 3);
            GLDS16(gp, (char*)xs + (size_t)g*1024);
        }
        if (wv == 0 && l < 48) {                  // remainder: chunks 768..815
            const int c = 768 + l;
            const int row = c >> 3, ckp = c & 7;
            const int r3 = row / 34, px = row - r3*34;
            const int ck = ckp ^ (row & 7);
            const int sr = refl(h - 1 + r3, HH);
            const int sc = refl(w0 - 1 + px, WW);
            const unsigned short* gp = srcb + ((((size_t)b*HH + sr)*WW + sc) << 6) + (ck << 3);
            GLDS16(gp, (char*)xs + (size_t)12*1024);
        }
    } else {
        const int q = tid & 3;
        for (int s0 = tid >> 2; s0 < 102; s0 += 64) {
            const int r3 = s0 / 34, wi = s0 - r3*34;
            const int sr = refl(h - 1 + r3, HH);
            const int sc = refl(w0 - 1 + wi, WW);
            const size_t pix = ((size_t)b*HH + sr)*WW + sc;
            const float* p = xinf + pix*64 + q*16;
            f4 a0 = *(const f4*)p, a1 = *(const f4*)(p+4);
            f4 a2 = *(const f4*)(p+8), a3 = *(const f4*)(p+12);
            ushort8 o0, o1;
            o0[0]=f2b(a0.x); o0[1]=f2b(a0.y); o0[2]=f2b(a0.z); o0[3]=f2b(a0.w);
            o0[4]=f2b(a1.x); o0[5]=f2b(a1.y); o0[6]=f2b(a1.z); o0[7]=f2b(a1.w);
            o1[0]=f2b(a2.x); o1[1]=f2b(a2.y); o1[2]=f2b(a2.z); o1[3]=f2b(a2.w);
            o1[4]=f2b(a3.x); o1[5]=f2b(a3.y); o1[6]=f2b(a3.z); o1[7]=f2b(a3.w);
            const int row = r3*34 + wi;
            *(ushort8*)(xs + xrow(row, 2*q))     = o0;
            *(ushort8*)(xs + xrow(row, 2*q + 1)) = o1;
        }
    }
    for (int j = tid; j < 288; j += NTH)
        ((f4*)wcvb)[j] = ((const f4*)wcbg)[j];
    if (tid < TPX) {
        const size_t pix = (size_t)R * WW + w0 + tid;
        lgs[TPX + tid] = (rnd[pix] > 0.5f) ? 1.f : 0.f;
        if (SRCF == 0)
            lgs[tid] = (xinf[pix*64] > 0.f) ? 1.f : 0.f;
    }
    __syncthreads();                                          // B1 (drains vmcnt)

    if (SRCF == 1 && tid < TPX)
        lgs[tid] = (b2f(xs[xrow(34 + tid + 1, 0)]) > 0.f) ? 1.f : 0.f;

    // ---- phase 2: conv features -> Fc (swizzled); fp32 weights (broadcast LDS) ----
    {
        const int px = tid >> 3, ck = tid & 7, cg = ck * 8;
        float a1[8], a2[8];
        #pragma unroll
        for (int k = 0; k < 8; ++k) { a1[k] = 0.f; a2[k] = 0.f; }
        #pragma unroll
        for (int t = 0; t < 9; ++t) {             // t = i2*3 + j
            const int i2 = t / 3, j = t - 3*i2;
            const ushort8 xv = *(const ushort8*)(xs + xrow(j*34 + px + i2, ck));
            const float* w1p = wcvb + t*64 + cg;
            const float* w2p = wcvb + 576 + t*64 + cg;
            #pragma unroll
            for (int k = 0; k < 8; ++k) {
                const float xf = b2f(xv[k]);
                a1[k] = fmaf(xf, w1p[k], a1[k]);
                a2[k] = fmaf(xf, w2p[k], a2[k]);
            }
        }
        ushort8 o1v, o2v;
        #pragma unroll
        for (int k = 0; k < 8; ++k) { o1v[k] = f2b(a1[k]); o2v[k] = f2b(a2[k]); }
        const int sw = (px & 7) << 4;
        *(ushort8*)(fch + ((px*256 + cg*2) ^ sw))       = o1v;
        *(ushort8*)(fch + ((px*256 + 128 + cg*2) ^ sw)) = o2v;
    }
    __syncthreads();                                          // B2

    // ---- phase 3: GEMM1; wave wv owns o-slice [wv*64, wv*64+64), Mt=2 x Ot=4 ----
    f4 acc[2][4];
    #pragma unroll
    for (int ot = 0; ot < 4; ++ot) {
        const float bv = bh[wv*64 + ot*16 + lr];
        const f4 bvv = {bv, bv, bv, bv};
        acc[0][ot] = bvv; acc[1][ot] = bvv;
    }
    #pragma unroll
    for (int ks = 0; ks < 6; ++ks) {
        short8 afr[2];
        #pragma unroll
        for (int mt = 0; mt < 2; ++mt) {
            const int px = mt*16 + lr;
            if (ks < 2)    // x-features from halo center row
                afr[mt] = *(const short8*)(xs + xrow(34 + px + 1, ks*4 + gq));
            else
                afr[mt] = *(const short8*)(fch +
                            ((px*256 + (ks-2)*64 + gq*16) ^ ((px & 7) << 4)));
        }
        #pragma unroll
        for (int ot = 0; ot < 4; ++ot) {
            const short8 bfr = *(const short8*)(wtp + ((((wv*4 + ot)*6 + ks)*64 + l) << 3));
            acc[0][ot] = __builtin_amdgcn_mfma_f32_16x16x32_bf16(afr[0], bfr, acc[0][ot], 0,0,0);
            acc[1][ot] = __builtin_amdgcn_mfma_f32_16x16x32_bf16(afr[1], bfr, acc[1][ot], 0,0,0);
        }
    }

    // epilogue base values from xs (still intact; all 64 channels valid)
    const int mh = wv >> 1, cs = wv & 1;     // GEMM2 mapping: px-half, c-half
    unsigned short baseb[8];
    #pragma unroll
    for (int ct = 0; ct < 2; ++ct)
      #pragma unroll
      for (int r2 = 0; r2 < 4; ++r2) {
        const int px = mh*16 + gq*4 + r2;
        const int c  = cs*32 + ct*16 + lr;
        baseb[ct*4 + r2] = xs[xrow(34 + px + 1, c >> 3) + (c & 7)];
      }
    __syncthreads();                                          // B3 (xs/Fc reads done)

    // h (bf16, swizzled 512B rows) overlays [0, 16384)
    #pragma unroll
    for (int mt = 0; mt < 2; ++mt)
      #pragma unroll
      for (int ot = 0; ot < 4; ++ot)
        #pragma unroll
        for (int r2 = 0; r2 < 4; ++r2) {
            const int px = mt*16 + gq*4 + r2;
            const int o  = wv*64 + ot*16 + lr;
            *(unsigned short*)(smem + ((px*512 + o*2) ^ ((px & 7) << 4))) =
                f2b(fmaxf(acc[mt][ot][r2], 0.f));
        }
    __syncthreads();                                          // B4

    // ---- phase 4: GEMM2; wave = (px-half mh, c-half cs), Mt=1 x Ct=2 ----
    f4 acc2[2] = {{0.f,0.f,0.f,0.f},{0.f,0.f,0.f,0.f}};
    #pragma unroll
    for (int ks2 = 0; ks2 < 8; ++ks2) {
        const int px = mh*16 + lr;
        const short8 ha = *(const short8*)(smem + ((px*512 + ks2*64 + gq*16) ^ ((px & 7) << 4)));
        #pragma unroll
        for (int ct = 0; ct < 2; ++ct) {
            const short8 bw = *(const short8*)(wfp + ((((cs*2 + ct)*8 + ks2)*64 + l) << 3));
            acc2[ct] = __builtin_amdgcn_mfma_f32_16x16x32_bf16(ha, bw, acc2[ct], 0,0,0);
        }
    }

    // ---- epilogue: gate + mask + life -> stage @16384 (disjoint from h) ----
    unsigned short* stageB = (unsigned short*)stg;   // DSTF==0: [32][64] bf16
    float*          stageF = (float*)stg;            // DSTF==1: [32][64] fp32
    #pragma unroll
    for (int ct = 0; ct < 2; ++ct)
      #pragma unroll
      for (int r2 = 0; r2 < 4; ++r2) {
        const int px = mh*16 + gq*4 + r2;
        const int c  = cs*32 + ct*16 + lr;
        const float life = lgs[px], g = lgs[TPX + px];
        const float base = b2f(baseb[ct*4 + r2]);
        const float dx   = acc2[ct][r2];
        const float outv = (c >= 4) ? (base + dx * g) * life : base * life;
        if (DSTF == 1) stageF[px*64 + c] = outv;
        else           stageB[px*64 + c] = f2b(outv);
      }
    __syncthreads();                                          // B5

    // ---- coalesced full-line store (non-temporal; dst has no reuse) ----
    const size_t pix0 = (size_t)R * WW + w0;
    if (DSTF == 1) {
        float* dstf = (float*)dstv + pix0 * 64;
        for (int i = tid; i < 512; i += NTH) {
            const f4 v = *(const f4*)(stageF + i*4);
            __builtin_nontemporal_store(v, (f4*)(dstf + i*4));
        }
    } else {
        unsigned short* dstb = (unsigned short*)dstv + pix0 * 64;
        const ushort8 v = *(const ushort8*)(stageB + tid*8);
        __builtin_nontemporal_store(v, (ushort8*)(dstb + tid*8));
    }
}

extern "C" void kernel_launch(void* const* d_in, const int* in_sizes, int n_in,
                              void* d_out, int out_size, void* d_ws, size_t ws_size,
                              hipStream_t stream) {
    const float* xin = (const float*)d_in[0];
    const float* w1  = (const float*)d_in[1];
    const float* w2  = (const float*)d_in[2];
    const float* wh  = (const float*)d_in[3];
    const float* bh  = (const float*)d_in[4];
    const float* wf  = (const float*)d_in[5];
    const float* rv  = (const float*)d_in[6];

    unsigned short* wtp = (unsigned short*)((char*)d_ws + WS_WTP);
    unsigned short* wfp = (unsigned short*)((char*)d_ws + WS_WFP);
    float*          wcb = (float*)((char*)d_ws + WS_WCB);
    unsigned short* stb = (unsigned short*)((char*)d_ws + WS_ST);   // bf16 state A
    unsigned short* omb = (unsigned short*)d_out;                   // bf16 state B (scratch)

    prep <<<dim3(32), dim3(256), 0, stream>>>(wh, wf, wtp, wfp);
    prep2<<<dim3(5),  dim3(256), 0, stream>>>(w1, w2, wcb);

    dim3 g(WW / TPX, HH, BB), blk(NTH);
    nca_step<0,0><<<g, blk, 0, stream>>>(xin, nullptr, stb, wtp, wfp, wcb, bh, rv);
    for (int s = 1; s < 7; ++s) {
        const unsigned short* sp = (s & 1) ? stb : omb;
        unsigned short* dp       = (s & 1) ? omb : stb;
        nca_step<1,0><<<g, blk, 0, stream>>>(nullptr, sp, dp, wtp, wfp, wcb, bh,
                                             rv + (size_t)s * NPIX);
    }
    nca_step<1,1><<<g, blk, 0, stream>>>(nullptr, stb, d_out, wtp, wfp, wcb, bh,
                                         rv + (size_t)7 * NPIX);
}

// Round 22
// 580.898 us; speedup vs baseline: 1.3033x; 1.0502x over previous
//
#include <hip/hip_runtime.h>

#define BB 16
#define HH 128
#define WW 128
#define CH 64              // state channels, bf16, one 128B line per pixel
#define TPX 32             // tile width in pixels
#define NTH 256
#define NPIX (BB*HH*WW)
#define KF 192
#define HID 256

// workspace offsets (bytes)
#define WS_WTP 0u              // 98,304  : GEMM1 B-fragments bf16
#define WS_WFP 98304u          // 32,768  : GEMM2 B-fragments bf16
#define WS_WCB 131072u         //  4,608  : conv weights fp32 [2][9][64]
#define WS_ST  135680u         // 33,554,432 : bf16 state [NPIX][64]

typedef __attribute__((ext_vector_type(8))) short short8;
typedef __attribute__((ext_vector_type(8))) unsigned short ushort8;
typedef __attribute__((ext_vector_type(4))) float f4;
typedef __attribute__((ext_vector_type(2))) float f2;
typedef __attribute__((ext_vector_type(4))) unsigned int u32x4;

// LDS layout (bytes), 26,112 total -> 6 blocks/CU:
//   xs   [3][34][64]u16 dense 128B rows, chunk-XOR swizzled  @ 0      : 13,056
//   Fc   [32][128]u16 (XOR-swizzled rows)                    @ 13,056 :  8,192
//   h    [32][256]u16 swizzled 512B rows, overlays [0,16384) after B3
//   stage bf16/fp32 [32][64]                                 @ 16,384 :  8,192
//   wcvb fp32 [2][9][64]                                     @ 21,248 :  4,608
//   lgs  life[32]+gate[32] floats                            @ 25,856 :    256
#define OFF_FC  13056
#define OFF_STG 16384
#define OFF_WCV 21248
#define OFF_LG  25856
#define SMEM_SZ 26112

// async global->LDS 16B/lane: linear LDS dest (wave base + lane*16), per-lane global src
#define GLDS16(gp, lp) __builtin_amdgcn_global_load_lds( \
    (const __attribute__((address_space(1))) unsigned int*)(gp), \
    (__attribute__((address_space(3))) unsigned int*)(lp), 16, 0, 0)

__device__ __forceinline__ unsigned short f2b(float f) {   // fp32 -> bf16 RTNE (scalar)
    unsigned x = __float_as_uint(f);
    x += 0x7fffu + ((x >> 16) & 1u);
    return (unsigned short)(x >> 16);
}
// HW packed fp32->bf16 RTNE: lo16 = cvt(a), hi16 = cvt(b). Pure VALU, 1 inst / 2 values.
__device__ __forceinline__ unsigned cvtpk(float a, float b) {
    unsigned r;
    asm("v_cvt_pk_bf16_f32 %0, %1, %2" : "=v"(r) : "v"(a), "v"(b));
    return r;
}
__device__ __forceinline__ float b2f(unsigned short u) {
    return __uint_as_float(((unsigned)u) << 16);
}
__device__ __forceinline__ int refl(int i, int n) {
    if (i < 0) return -i;
    if (i >= n) return 2*n - 2 - i;
    return i;
}
// xs addressing: row (0..101), chunk (0..7); short-index of 16B chunk base.
// Row stride 64 shorts = 128B; chunk XOR (row&7) spreads banks (T2).
__device__ __forceinline__ int xrow(int row, int chunk) {
    return row*64 + (((chunk ^ row) & 7) << 3);
}

// prep: weights into MFMA B-fragment order (bf16). Verified layout (r4-r21).
__global__ __launch_bounds__(256) void prep(
    const float* __restrict__ wh, const float* __restrict__ wf,
    unsigned short* __restrict__ wtp, unsigned short* __restrict__ wfp)
{
    int i = blockIdx.x * 256 + threadIdx.x;   // 8192 groups
    if (i < 6144) {
        const int l = i & 63, r = i >> 6;
        const int ks = r % 6, ti = r / 6;
        const int row = ti*16 + (l & 15);
        const int k0  = ks*32 + (l >> 4)*8;
        ushort8 v;
        #pragma unroll
        for (int j = 0; j < 8; ++j) v[j] = f2b(wh[row*KF + k0 + j]);
        *(ushort8*)&wtp[(size_t)i * 8] = v;
    } else {
        const int g = i - 6144;               // 2048 groups
        const int l = g & 63, r = g >> 6;
        const int ks2 = r & 7, cq = r >> 3;
        const int c  = cq*16 + (l & 15);
        const int o0 = ks2*32 + (l >> 4)*8;
        ushort8 v;
        #pragma unroll
        for (int j = 0; j < 8; ++j) v[j] = f2b(wf[c*HID + o0 + j]);
        *(ushort8*)&wfp[(size_t)g * 8] = v;
    }
}

// prep2: conv weights -> fp32 [filter][tap][ch] (mapping verified r2-r21)
__global__ __launch_bounds__(256) void prep2(
    const float* __restrict__ w1, const float* __restrict__ w2,
    float* __restrict__ wcb)
{
    int i = blockIdx.x * 256 + threadIdx.x;
    if (i < 1152) {
        const int f = i / 576, rem = i - f * 576;
        const int t = rem >> 6, c = rem & 63;
        wcb[i] = (f ? w2 : w1)[c*9 + t];
    }
}

// SRCF: 0 = src is xin (64ch fp32 raw), 1 = src is bf16 state64 (line-aligned)
// DSTF: 0 = dst is bf16 state64, 1 = dst is out (64ch fp32)
template<int SRCF, int DSTF>
__global__ __launch_bounds__(256, 4) void nca_step(
    const float* __restrict__ xinf, const unsigned short* __restrict__ srcb,
    void* __restrict__ dstv,
    const unsigned short* __restrict__ wtp, const unsigned short* __restrict__ wfp,
    const float* __restrict__ wcbg,
    const float* __restrict__ bh, const float* __restrict__ rnd)
{
    __shared__ __align__(16) char smem[SMEM_SZ];
    unsigned short* xs   = (unsigned short*)smem;
    char*           fch  = smem + OFF_FC;
    char*           stg  = smem + OFF_STG;
    float*          wcvb = (float*)(smem + OFF_WCV);
    float*          lgs  = (float*)(smem + OFF_LG);

    const int tid = threadIdx.x;
    const int l = tid & 63, wv = tid >> 6;   // 4 waves
    const int lr = l & 15, gq = l >> 4;
    const int w0 = blockIdx.x * TPX;
    const int h  = blockIdx.y;
    const int b  = blockIdx.z;
    const int R  = b * HH + h;

    // ---- phase 1: halo staging (async DMA for state path), weights, gate ----
    if (SRCF == 1) {
        // linear LDS dest; inverse chunk-swizzle on SOURCE (rule 21); readers use xrow()
        #pragma unroll
        for (int it = 0; it < 3; ++it) {
            const int g = wv + it*4;              // 12 full wave-groups
            const int c = g*64 + l;
            const int row = c >> 3, ckp = c & 7;
            const int r3 = row / 34, px = row - r3*34;
            const int ck = ckp ^ (row & 7);
            const int sr = refl(h - 1 + r3, HH);
            const int sc = refl(w0 - 1 + px, WW);
            const unsigned short* gp = srcb + ((((size_t)b*HH + sr)*WW + sc) << 6) + (ck << 3);
            GLDS16(gp, (char*)xs + (size_t)g*1024);
        }
        if (wv == 0 && l < 48) {                  // remainder: chunks 768..815
            const int c = 768 + l;
            const int row = c >> 3, ckp = c & 7;
            const int r3 = row / 34, px = row - r3*34;
            const int ck = ckp ^ (row & 7);
            const int sr = refl(h - 1 + r3, HH);
            const int sc = refl(w0 - 1 + px, WW);
            const unsigned short* gp = srcb + ((((size_t)b*HH + sr)*WW + sc) << 6) + (ck << 3);
            GLDS16(gp, (char*)xs + (size_t)12*1024);
        }
    } else {
        const int q = tid & 3;
        for (int s0 = tid >> 2; s0 < 102; s0 += 64) {
            const int r3 = s0 / 34, wi = s0 - r3*34;
            const int sr = refl(h - 1 + r3, HH);
            const int sc = refl(w0 - 1 + wi, WW);
            const size_t pix = ((size_t)b*HH + sr)*WW + sc;
            const float* p = xinf + pix*64 + q*16;
            f4 a0 = *(const f4*)p, a1 = *(const f4*)(p+4);
            f4 a2 = *(const f4*)(p+8), a3 = *(const f4*)(p+12);
            u32x4 o0, o1;
            o0[0] = cvtpk(a0.x, a0.y); o0[1] = cvtpk(a0.z, a0.w);
            o0[2] = cvtpk(a1.x, a1.y); o0[3] = cvtpk(a1.z, a1.w);
            o1[0] = cvtpk(a2.x, a2.y); o1[1] = cvtpk(a2.z, a2.w);
            o1[2] = cvtpk(a3.x, a3.y); o1[3] = cvtpk(a3.z, a3.w);
            const int row = r3*34 + wi;
            *(u32x4*)(xs + xrow(row, 2*q))     = o0;
            *(u32x4*)(xs + xrow(row, 2*q + 1)) = o1;
        }
    }
    for (int j = tid; j < 288; j += NTH)
        ((f4*)wcvb)[j] = ((const f4*)wcbg)[j];
    if (tid < TPX) {
        const size_t pix = (size_t)R * WW + w0 + tid;
        lgs[TPX + tid] = (rnd[pix] > 0.5f) ? 1.f : 0.f;
        if (SRCF == 0)
            lgs[tid] = (xinf[pix*64] > 0.f) ? 1.f : 0.f;
    }
    __syncthreads();                                          // B1 (drains vmcnt)

    if (SRCF == 1 && tid < TPX)
        lgs[tid] = (b2f(xs[xrow(34 + tid + 1, 0)]) > 0.f) ? 1.f : 0.f;

    // ---- phase 2: conv -> Fc; packed f32 FMA (v_pk_fma_f32) + cvt_pk pack ----
    {
        const int px = tid >> 3, ck = tid & 7, cg = ck * 8;
        f2 a1[4], a2[4];
        #pragma unroll
        for (int k2 = 0; k2 < 4; ++k2) { a1[k2] = (f2){0.f,0.f}; a2[k2] = (f2){0.f,0.f}; }
        #pragma unroll
        for (int t = 0; t < 9; ++t) {             // t = i2*3 + j
            const int i2 = t / 3, j = t - 3*i2;
            const u32x4 xv = *(const u32x4*)(xs + xrow(j*34 + px + i2, ck));
            const f2* w1p = (const f2*)(wcvb + t*64 + cg);
            const f2* w2p = (const f2*)(wcvb + 576 + t*64 + cg);
            #pragma unroll
            for (int k2 = 0; k2 < 4; ++k2) {
                const unsigned d = xv[k2];
                f2 xf;
                xf.x = __uint_as_float(d << 16);
                xf.y = __uint_as_float(d & 0xffff0000u);
                a1[k2] = __builtin_elementwise_fma(xf, w1p[k2], a1[k2]);
                a2[k2] = __builtin_elementwise_fma(xf, w2p[k2], a2[k2]);
            }
        }
        u32x4 o1v, o2v;
        #pragma unroll
        for (int k2 = 0; k2 < 4; ++k2) {
            o1v[k2] = cvtpk(a1[k2].x, a1[k2].y);
            o2v[k2] = cvtpk(a2[k2].x, a2[k2].y);
        }
        const int sw = (px & 7) << 4;
        *(u32x4*)(fch + ((px*256 + cg*2) ^ sw))       = o1v;
        *(u32x4*)(fch + ((px*256 + 128 + cg*2) ^ sw)) = o2v;
    }
    __syncthreads();                                          // B2

    // ---- phase 3: GEMM1; wave wv owns o-slice [wv*64, wv*64+64), Mt=2 x Ot=4 ----
    f4 acc[2][4];
    #pragma unroll
    for (int ot = 0; ot < 4; ++ot) {
        const float bv = bh[wv*64 + ot*16 + lr];
        const f4 bvv = {bv, bv, bv, bv};
        acc[0][ot] = bvv; acc[1][ot] = bvv;
    }
    #pragma unroll
    for (int ks = 0; ks < 6; ++ks) {
        short8 afr[2];
        #pragma unroll
        for (int mt = 0; mt < 2; ++mt) {
            const int px = mt*16 + lr;
            if (ks < 2)    // x-features from halo center row
                afr[mt] = *(const short8*)(xs + xrow(34 + px + 1, ks*4 + gq));
            else
                afr[mt] = *(const short8*)(fch +
                            ((px*256 + (ks-2)*64 + gq*16) ^ ((px & 7) << 4)));
        }
        #pragma unroll
        for (int ot = 0; ot < 4; ++ot) {
            const short8 bfr = *(const short8*)(wtp + ((((wv*4 + ot)*6 + ks)*64 + l) << 3));
            acc[0][ot] = __builtin_amdgcn_mfma_f32_16x16x32_bf16(afr[0], bfr, acc[0][ot], 0,0,0);
            acc[1][ot] = __builtin_amdgcn_mfma_f32_16x16x32_bf16(afr[1], bfr, acc[1][ot], 0,0,0);
        }
    }

    // epilogue base values from xs (still intact; all 64 channels valid)
    const int mh = wv >> 1, cs = wv & 1;     // GEMM2 mapping: px-half, c-half
    unsigned short baseb[8];
    #pragma unroll
    for (int ct = 0; ct < 2; ++ct)
      #pragma unroll
      for (int r2 = 0; r2 < 4; ++r2) {
        const int px = mh*16 + gq*4 + r2;
        const int c  = cs*32 + ct*16 + lr;
        baseb[ct*4 + r2] = xs[xrow(34 + px + 1, c >> 3) + (c & 7)];
      }
    __syncthreads();                                          // B3 (xs/Fc reads done)

    // h (bf16, swizzled 512B rows) overlays [0, 16384); cvt_pk pairs + hi-extract
    #pragma unroll
    for (int mt = 0; mt < 2; ++mt)
      #pragma unroll
      for (int ot = 0; ot < 4; ++ot) {
        const unsigned p01 = cvtpk(fmaxf(acc[mt][ot][0], 0.f), fmaxf(acc[mt][ot][1], 0.f));
        const unsigned p23 = cvtpk(fmaxf(acc[mt][ot][2], 0.f), fmaxf(acc[mt][ot][3], 0.f));
        const int o = wv*64 + ot*16 + lr;
        const int px0 = mt*16 + gq*4;
        *(unsigned short*)(smem + (((px0+0)*512 + o*2) ^ (((px0+0) & 7) << 4))) = (unsigned short)p01;
        *(unsigned short*)(smem + (((px0+1)*512 + o*2) ^ (((px0+1) & 7) << 4))) = (unsigned short)(p01 >> 16);
        *(unsigned short*)(smem + (((px0+2)*512 + o*2) ^ (((px0+2) & 7) << 4))) = (unsigned short)p23;
        *(unsigned short*)(smem + (((px0+3)*512 + o*2) ^ (((px0+3) & 7) << 4))) = (unsigned short)(p23 >> 16);
      }
    __syncthreads();                                          // B4

    // ---- phase 4: GEMM2; wave = (px-half mh, c-half cs), Mt=1 x Ct=2 ----
    f4 acc2[2] = {{0.f,0.f,0.f,0.f},{0.f,0.f,0.f,0.f}};
    #pragma unroll
    for (int ks2 = 0; ks2 < 8; ++ks2) {
        const int px = mh*16 + lr;
        const short8 ha = *(const short8*)(smem + ((px*512 + ks2*64 + gq*16) ^ ((px & 7) << 4)));
        #pragma unroll
        for (int ct = 0; ct < 2; ++ct) {
            const short8 bw = *(const short8*)(wfp + ((((cs*2 + ct)*8 + ks2)*64 + l) << 3));
            acc2[ct] = __builtin_amdgcn_mfma_f32_16x16x32_bf16(ha, bw, acc2[ct], 0,0,0);
        }
    }

    // ---- epilogue: gate + mask + life -> stage @16384 (disjoint from h) ----
    unsigned short* stageB = (unsigned short*)stg;   // DSTF==0: [32][64] bf16
    float*          stageF = (float*)stg;            // DSTF==1: [32][64] fp32
    #pragma unroll
    for (int r2 = 0; r2 < 4; ++r2) {
        const int px = mh*16 + gq*4 + r2;
        const float life = lgs[px], g = lgs[TPX + px];
        float outv[2];
        #pragma unroll
        for (int ct = 0; ct < 2; ++ct) {
            const int c  = cs*32 + ct*16 + lr;
            const float base = b2f(baseb[ct*4 + r2]);
            const float dx   = acc2[ct][r2];
            outv[ct] = (c >= 4) ? (base + dx * g) * life : base * life;
        }
        const int c0 = cs*32 + lr;
        if (DSTF == 1) {
            stageF[px*64 + c0]      = outv[0];
            stageF[px*64 + c0 + 16] = outv[1];
        } else {
            const unsigned p = cvtpk(outv[0], outv[1]);
            stageB[px*64 + c0]      = (unsigned short)p;
            stageB[px*64 + c0 + 16] = (unsigned short)(p >> 16);
        }
    }
    __syncthreads();                                          // B5

    // ---- coalesced full-line store (non-temporal; dst has no reuse) ----
    const size_t pix0 = (size_t)R * WW + w0;
    if (DSTF == 1) {
        float* dstf = (float*)dstv + pix0 * 64;
        for (int i = tid; i < 512; i += NTH) {
            const f4 v = *(const f4*)(stageF + i*4);
            __builtin_nontemporal_store(v, (f4*)(dstf + i*4));
        }
    } else {
        unsigned short* dstb = (unsigned short*)dstv + pix0 * 64;
        const ushort8 v = *(const ushort8*)(stageB + tid*8);
        __builtin_nontemporal_store(v, (ushort8*)(dstb + tid*8));
    }
}

extern "C" void kernel_launch(void* const* d_in, const int* in_sizes, int n_in,
                              void* d_out, int out_size, void* d_ws, size_t ws_size,
                              hipStream_t stream) {
    const float* xin = (const float*)d_in[0];
    const float* w1  = (const float*)d_in[1];
    const float* w2  = (const float*)d_in[2];
    const float* wh  = (const float*)d_in[3];
    const float* bh  = (const float*)d_in[4];
    const float* wf  = (const float*)d_in[5];
    const float* rv  = (const float*)d_in[6];

    unsigned short* wtp = (unsigned short*)((char*)d_ws + WS_WTP);
    unsigned short* wfp = (unsigned short*)((char*)d_ws + WS_WFP);
    float*          wcb = (float*)((char*)d_ws + WS_WCB);
    unsigned short* stb = (unsigned short*)((char*)d_ws + WS_ST);   // bf16 state A
    unsigned short* omb = (unsigned short*)d_out;                   // bf16 state B (scratch)

    prep <<<dim3(32), dim3(256), 0, stream>>>(wh, wf, wtp, wfp);
    prep2<<<dim3(5),  dim3(256), 0, stream>>>(w1, w2, wcb);

    dim3 g(WW / TPX, HH, BB), blk(NTH);
    nca_step<0,0><<<g, blk, 0, stream>>>(xin, nullptr, stb, wtp, wfp, wcb, bh, rv);
    for (int s = 1; s < 7; ++s) {
        const unsigned short* sp = (s & 1) ? stb : omb;
        unsigned short* dp       = (s & 1) ? omb : stb;
        nca_step<1,0><<<g, blk, 0, stream>>>(nullptr, sp, dp, wtp, wfp, wcb, bh,
                                             rv + (size_t)s * NPIX);
    }
    nca_step<1,1><<<g, blk, 0, stream>>>(nullptr, stb, d_out, wtp, wfp, wcb, bh,
                                         rv + (size_t)7 * NPIX);
}